// Round 10
// baseline (216.116 us; speedup 1.0000x reference)
//
#include <hip/hip_runtime.h>
#include <math.h>

#define NEG_SLOPE 0.2f
#define EPSF 1e-16f

constexpr int FIN = 128;
constexpr int H   = 64;
constexpr int C   = 2;
constexpr int BSHIFT = 7;               // nodes per bucket = 128 (occupancy: 782 blocks)
constexpr int NPB = 1 << BSHIFT;        // nodes per bucket
constexpr int NBUCK_MAX = 1024;         // supports N <= 128k at BSHIFT=7
constexpr int CHUNK = 4096;             // edges per stage block
constexpr int CAP   = 6144;             // max edges per bucket for LDS fast path (mean 2048)

typedef short v8s __attribute__((ext_vector_type(8)));
typedef float v4f __attribute__((ext_vector_type(4)));
typedef unsigned short u16;

// round-to-nearest-even fp32 -> bf16 split (hi + lo captures ~17 mantissa bits)
__device__ inline void split_bf16(float v, u16& hi, u16& lo) {
    unsigned u = __float_as_uint(v);
    unsigned r = (u + 0x7FFFu + ((u >> 16) & 1u)) >> 16;
    hi = (u16)r;
    float hf = __uint_as_float(r << 16);
    float l = v - hf;
    unsigned ul = __float_as_uint(l);
    lo = (u16)((ul + 0x7FFFu + ((ul >> 16) & 1u)) >> 16);
}

__device__ inline u16 to_bf16(float v) {
    unsigned u = __float_as_uint(v);
    return (u16)((u + 0x7FFFu + ((u >> 16) & 1u)) >> 16);
}
__device__ inline float blo(int v) { return __uint_as_float((unsigned)v << 16); }
__device__ inline float bhi(int v) { return __uint_as_float((unsigned)v & 0xFFFF0000u); }

// exclusive prefix over a 1024-thread block via wave shfl scans.
// wtot must be 16 ints of LDS. Internal barrier; caller must barrier before
// reusing wtot.
__device__ inline int scan1024_excl(int v, int* wtot, int t) {
    int lane = t & 63, w = t >> 6;
    int incl = v;
    #pragma unroll
    for (int o = 1; o < 64; o <<= 1) {
        int u = __shfl_up(incl, o, 64);
        if (lane >= o) incl += u;
    }
    if (lane == 63) wtot[w] = incl;
    __syncthreads();
    int woff = 0;
    for (int i = 0; i < w; i++) woff += wtot[i];
    return woff + incl - v;
}

// ---------- pre: one chunk per block (1024 thr). ea chunk-sum + histogram + W1 prep ----------
// Wt is written in MFMA *fragment order*: element (k, f) -> flat u16 index
//   (k>>3)*512 + f*8 + (k&7)
__global__ __launch_bounds__(1024) void pre_kernel(const float* __restrict__ ea,
                                                   const int* __restrict__ dst, int E,
                                                   float* __restrict__ csum, int* __restrict__ cnt,
                                                   const float* __restrict__ W1,
                                                   u16* __restrict__ Wt_hi, u16* __restrict__ Wt_lo,
                                                   int NBUCK) {
    int c = blockIdx.x, t = threadIdx.x;
    int gid = c * 1024 + t;
    if (gid < FIN * H) {                      // W1 prep: first 8 blocks
        int k = gid >> 6, f = gid & 63;       // W1 is [k][f]
        u16 h, l;
        split_bf16(W1[gid], h, l);
        int idx = ((k >> 3) << 9) + (f << 3) + (k & 7);   // fragment order
        Wt_hi[idx] = h;
        Wt_lo[idx] = l;
    }
    __shared__ int lh[NBUCK_MAX];
    __shared__ float wsum[16];
    lh[t] = 0;
    __syncthreads();
    int base = c * CHUNK;
    int cntE = min(CHUNK, E - base);
    float acc = 0.f;
    for (int i = t; i < cntE; i += 1024) {
        int e = base + i;
        acc += ea[e];
        atomicAdd(&lh[dst[e] >> BSHIFT], 1);
    }
    for (int off = 32; off; off >>= 1) acc += __shfl_down(acc, off, 64);
    int lane = t & 63, wv = t >> 6;
    if (lane == 0) wsum[wv] = acc;
    __syncthreads();                          // covers lh atomics + wsum
    if (t == 0) {
        float s = 0.f;
        #pragma unroll
        for (int i = 0; i < 16; i++) s += wsum[i];
        csum[c] = s;                          // plain store, no global atomic
    }
    if (t < NBUCK) cnt[(size_t)c * NBUCK + t] = lh[t];
}

// ---------- soff: per-bucket scan over chunks -> poff[b][c], bcount[b]; block 0: scalars ----------
__global__ __launch_bounds__(256) void soff_kernel(const int* __restrict__ cnt,
                                                   int NBUCK, int NCHUNK,
                                                   int* __restrict__ bcount, int* __restrict__ poff,
                                                   const float* __restrict__ csum, int E,
                                                   const float* __restrict__ W_edge1,
                                                   const float* __restrict__ att_edge1,
                                                   const float* __restrict__ W_edge2,
                                                   const float* __restrict__ att_edge2,
                                                   float* __restrict__ scal,
                                                   int* __restrict__ rowN) {
    int b = blockIdx.x, t = threadIdx.x;
    int per = (NCHUNK + 255) / 256;           // chunks per thread (2 for NCHUNK=391)
    int v[8];                                 // supports NCHUNK <= 2048
    int s = 0;
    for (int j = 0; j < per; j++) {
        int c = t * per + j;
        v[j] = (c < NCHUNK) ? cnt[(size_t)c * NBUCK + b] : 0;
        s += v[j];
    }
    __shared__ int red[256];
    __shared__ float ws4[4];
    red[t] = s;
    __syncthreads();
    for (int off = 1; off < 256; off <<= 1) {
        int u = (t >= off) ? red[t - off] : 0;
        __syncthreads();
        red[t] += u;
        __syncthreads();
    }
    int run = red[t] - s;
    for (int j = 0; j < per; j++) {
        int c = t * per + j;
        if (c < NCHUNK) poff[(size_t)b * NCHUNK + c] = run;
        run += v[j];
    }
    if (t == 255) bcount[b] = red[255];
    if (b == 0) {                             // absorbed scalar work
        float acc = 0.f;
        for (int i = t; i < NCHUNK; i += 256) acc += csum[i];
        for (int off = 32; off; off >>= 1) acc += __shfl_down(acc, off, 64);
        if ((t & 63) == 0) ws4[t >> 6] = acc;
        __syncthreads();
        if (t == 0) {
            float tot = ws4[0] + ws4[1] + ws4[2] + ws4[3];
            float c1 = 0.f;
            for (int i = 0; i < H; i++) c1 += W_edge1[i] * att_edge1[i];
            float c2 = 0.f;
            for (int i = 0; i < C; i++) c2 += W_edge2[i] * att_edge2[i];
            scal[0] = tot / (float)E; scal[1] = c1; scal[2] = c2;
            *rowN = E;
        }
    }
}

// ---------- stage: bucket-major reorder (1024 thr); block 0 publishes bbase ----------
__global__ __launch_bounds__(1024) void stage_kernel(
        const int* __restrict__ src, const int* __restrict__ dst, const float* __restrict__ ea,
        int E, const int* __restrict__ cnt, const int* __restrict__ poff,
        const int* __restrict__ bcount,
        int2* __restrict__ staging, int* __restrict__ bbase_out, int NBUCK, int NCHUNK) {
    __shared__ int   bb[NBUCK_MAX];
    __shared__ int   cur[NBUCK_MAX];
    __shared__ int   gofs[NBUCK_MAX];
    __shared__ int2  sbuf[CHUNK];
    __shared__ short sbkt[CHUNK];
    __shared__ int   wt16[16];
    int t = threadIdx.x;
    int c = blockIdx.x;
    int base = c * CHUNK;
    int cntE = min(CHUNK, E - base);
    // in-block exclusive scan of bucket totals -> bb
    int bv = (t < NBUCK) ? bcount[t] : 0;
    int bx = scan1024_excl(bv, wt16, t);
    if (t < NBUCK) bb[t] = bx;
    if (c == 0) {                             // publish for bfin_agg1 (runs after stage)
        if (t < NBUCK) bbase_out[t] = bx;
        if (t == 0) bbase_out[NBUCK] = E;
    }
    __syncthreads();                          // wt16 reuse + bb visibility
    // local per-chunk histogram scan (1 bucket/thread)
    int h = (t < NBUCK) ? cnt[(size_t)c * NBUCK + t] : 0;
    int p = scan1024_excl(h, wt16, t);
    if (t < NBUCK) {
        if (h) gofs[t] = bb[t] + poff[(size_t)t * NCHUNK + c] - p;
        cur[t] = p;
    }
    __syncthreads();
    // reorder into LDS
    for (int i = t; i < cntE; i += 1024) {
        int e = base + i;
        int d = dst[e];
        int b = d >> BSHIFT;
        int slot = atomicAdd(&cur[b], 1);
        sbuf[slot] = make_int2(src[e] | ((d & (NPB - 1)) << 20), __float_as_int(ea[e]));
        sbkt[slot] = (short)b;
    }
    __syncthreads();
    // coalesced write-out
    for (int j = t; j < cntE; j += 1024)
        staging[gofs[sbkt[j]] + j] = sbuf[j];
}

// ---------- layer 1 GEMM: 2 m-tiles per wave (32 nodes), W staged in LDS ----------
__global__ __launch_bounds__(256) void gemm1_mfma_kernel(
        const float* __restrict__ x,
        const u16* __restrict__ Wt_hi, const u16* __restrict__ Wt_lo,
        const float* __restrict__ att_src, const float* __restrict__ att_dst,
        u16* __restrict__ h1b, float* __restrict__ a_s, float* __restrict__ a_d, int N) {
    __shared__ u16 WhL[FIN * H];   // 16 KB, fragment-ordered
    __shared__ u16 WlL[FIN * H];   // 16 KB
    int t = threadIdx.x;
    int w = t >> 6, lane = t & 63;
    int m = lane & 15, q = lane >> 4;
    int base = blockIdx.x * 128 + w * 32;    // wave owns 32 nodes (2 tiles of 16)
    int n0 = base + m;                        // tile-0 A row
    int n1 = base + 16 + m;                   // tile-1 A row
    bool in0 = n0 < N, in1 = n1 < N;
    const float* xr0 = x + (size_t)n0 * FIN;
    const float* xr1 = x + (size_t)n1 * FIN;

    // issue W-fill loads (L2-resident, 32 KB/block) and both x-row loads so
    // their latencies overlap; split while loads land.
    float4 fh[4], fl4[4];
    {
        const float4* gh = (const float4*)Wt_hi;
        const float4* gl = (const float4*)Wt_lo;
        #pragma unroll
        for (int i = 0; i < 4; i++) {
            fh[i]  = gh[t + i * 256];
            fl4[i] = gl[t + i * 256];
        }
    }
    float4 xa[8], xb[8];
    #pragma unroll
    for (int kt = 0; kt < 4; kt++) {
        if (in0) {
            const float4* p = (const float4*)(xr0 + kt * 32 + q * 8);
            xa[kt * 2] = p[0]; xa[kt * 2 + 1] = p[1];
        } else {
            xa[kt * 2] = make_float4(0.f, 0.f, 0.f, 0.f);
            xa[kt * 2 + 1] = make_float4(0.f, 0.f, 0.f, 0.f);
        }
        if (in1) {
            const float4* p = (const float4*)(xr1 + kt * 32 + q * 8);
            xb[kt * 2] = p[0]; xb[kt * 2 + 1] = p[1];
        } else {
            xb[kt * 2] = make_float4(0.f, 0.f, 0.f, 0.f);
            xb[kt * 2 + 1] = make_float4(0.f, 0.f, 0.f, 0.f);
        }
    }
    {
        float4* sh = (float4*)WhL;
        float4* sl = (float4*)WlL;
        #pragma unroll
        for (int i = 0; i < 4; i++) {
            sh[t + i * 256] = fh[i];
            sl[t + i * 256] = fl4[i];
        }
    }

    v8s ah0[4], al0[4], ah1[4], al1[4];
    #pragma unroll
    for (int kt = 0; kt < 4; kt++) {
        float va[8], vb[8];
        va[0] = xa[kt*2].x; va[1] = xa[kt*2].y; va[2] = xa[kt*2].z; va[3] = xa[kt*2].w;
        va[4] = xa[kt*2+1].x; va[5] = xa[kt*2+1].y; va[6] = xa[kt*2+1].z; va[7] = xa[kt*2+1].w;
        vb[0] = xb[kt*2].x; vb[1] = xb[kt*2].y; vb[2] = xb[kt*2].z; vb[3] = xb[kt*2].w;
        vb[4] = xb[kt*2+1].x; vb[5] = xb[kt*2+1].y; vb[6] = xb[kt*2+1].z; vb[7] = xb[kt*2+1].w;
        #pragma unroll
        for (int j = 0; j < 8; j++) {
            u16 hb, lb;
            split_bf16(va[j], hb, lb);
            ah0[kt][j] = (short)hb; al0[kt][j] = (short)lb;
            split_bf16(vb[j], hb, lb);
            ah1[kt][j] = (short)hb; al1[kt][j] = (short)lb;
        }
    }
    __syncthreads();

    float ps0[4] = {0,0,0,0}, pd0[4] = {0,0,0,0};
    float ps1[4] = {0,0,0,0}, pd1[4] = {0,0,0,0};
    #pragma unroll
    for (int ft = 0; ft < 4; ft++) {
        v4f acc0 = {0.f, 0.f, 0.f, 0.f};
        v4f acc1 = {0.f, 0.f, 0.f, 0.f};
        #pragma unroll
        for (int kt = 0; kt < 4; kt++) {
            // fragment (ft,kt,q,m): u16 index (kt*4+q)*512 + (ft*16+m)*8
            int fi = ((kt * 4 + q) << 9) + ((ft * 16 + m) << 3);
            v8s bh = *(const v8s*)(WhL + fi);
            v8s bl = *(const v8s*)(WlL + fi);
            acc0 = __builtin_amdgcn_mfma_f32_16x16x32_bf16(ah0[kt], bh, acc0, 0, 0, 0);
            acc0 = __builtin_amdgcn_mfma_f32_16x16x32_bf16(al0[kt], bh, acc0, 0, 0, 0);
            acc0 = __builtin_amdgcn_mfma_f32_16x16x32_bf16(ah0[kt], bl, acc0, 0, 0, 0);
            acc1 = __builtin_amdgcn_mfma_f32_16x16x32_bf16(ah1[kt], bh, acc1, 0, 0, 0);
            acc1 = __builtin_amdgcn_mfma_f32_16x16x32_bf16(al1[kt], bh, acc1, 0, 0, 0);
            acc1 = __builtin_amdgcn_mfma_f32_16x16x32_bf16(ah1[kt], bl, acc1, 0, 0, 0);
        }
        int f = ft * 16 + m;               // C col
        float asf = att_src[f], adf = att_dst[f];
        #pragma unroll
        for (int r = 0; r < 4; r++) {      // C row = q*4 + r within each tile
            int nd0 = base + q * 4 + r;
            int nd1 = base + 16 + q * 4 + r;
            if (nd0 < N) h1b[(size_t)nd0 * H + f] = to_bf16(acc0[r]);
            if (nd1 < N) h1b[(size_t)nd1 * H + f] = to_bf16(acc1[r]);
            ps0[r] += acc0[r] * asf; pd0[r] += acc0[r] * adf;
            ps1[r] += acc1[r] * asf; pd1[r] += acc1[r] * adf;
        }
    }
    #pragma unroll
    for (int msk = 1; msk < 16; msk <<= 1) {
        #pragma unroll
        for (int r = 0; r < 4; r++) {
            ps0[r] += __shfl_xor(ps0[r], msk, 64);
            pd0[r] += __shfl_xor(pd0[r], msk, 64);
            ps1[r] += __shfl_xor(ps1[r], msk, 64);
            pd1[r] += __shfl_xor(pd1[r], msk, 64);
        }
    }
    if (m == 0) {
        #pragma unroll
        for (int r = 0; r < 4; r++) {
            int nd0 = base + q * 4 + r;
            int nd1 = base + 16 + q * 4 + r;
            if (nd0 < N) { a_s[nd0] = ps0[r]; a_d[nd0] = pd0[r]; }
            if (nd1 < N) { a_s[nd1] = ps1[r]; a_d[nd1] = pd1[r]; }
        }
    }
}

__device__ inline void accum8(float acc[8], float& den, float xw, int4 hv) {
    den += xw;
    acc[0] += xw * blo(hv.x); acc[1] += xw * bhi(hv.x);
    acc[2] += xw * blo(hv.y); acc[3] += xw * bhi(hv.y);
    acc[4] += xw * blo(hv.z); acc[5] += xw * bhi(hv.z);
    acc[6] += xw * blo(hv.w); acc[7] += xw * bhi(hv.w);
}

// ---------- bfin+agg1 fused (1024 thr): CSR rows + LDS sort + ex1 + layer1 agg + gemm2 ----------
// One block per 128-node bucket (BSHIFT=7). Sort phase keeps (sn,ex) in LDS,
// eav in abuf; sedge is written as (sn, eav) for agg2. Agg phase consumes the
// LDS edge list directly: 8-lane group per dst node, one 128-group round.
__global__ __launch_bounds__(1024) void bfin_agg1_kernel(
        const int2* __restrict__ staging, const int* __restrict__ bbase,
        const float* __restrict__ scal,
        const float* __restrict__ a_s1, const float* __restrict__ a_d1,
        const u16* __restrict__ h1b,
        const float* __restrict__ bias1, const float* __restrict__ W2,
        const float* __restrict__ att_src2, const float* __restrict__ att_dst2,
        int* __restrict__ row, int2* __restrict__ sedge,
        float* __restrict__ h2, float* __restrict__ a_s2, float* __restrict__ a_d2, int N) {
    __shared__ int   nh[256];
    __shared__ int   bg[256];
    __shared__ int   wt16[16];
    __shared__ int2  ebuf[CAP];    // 48 KB: (sn, ex)
    __shared__ float abuf[CAP];    // 24 KB: eav
    int b = blockIdx.x, t = threadIdx.x;
    int beg = bbase[b], end = bbase[b + 1];
    int cnt = end - beg;
    int node0 = b << BSHIFT;
    float c1 = scal[1];
    if (t < 256) nh[t] = 0;
    __syncthreads();
    for (int i = beg + t; i < end; i += 1024)
        atomicAdd(&nh[(unsigned)staging[i].x >> 20], 1);
    __syncthreads();
    // exclusive scan over the bins (bins >= NPB are zero; scan is generic)
    int v = (t < 256) ? nh[t] : 0;
    int lane = t & 63, w = t >> 6;
    int incl = v;
    #pragma unroll
    for (int o = 1; o < 64; o <<= 1) {
        int u = __shfl_up(incl, o, 64);
        if (lane >= o) incl += u;
    }
    if (w < 4 && lane == 63) wt16[w] = incl;
    __syncthreads();
    int woff = 0;
    int wl = w < 4 ? w : 4;
    for (int i = 0; i < wl; i++) woff += wt16[i];
    int excl = woff + incl - v;             // valid for t < 256
    if (t < NPB && node0 + t < N) row[node0 + t] = beg + excl;   // only this bucket's nodes!
    bool fast = (cnt <= CAP);
    if (t < 256) {
        bg[t] = excl;                        // start (relative for fast, offset for fallback)
        nh[t] = fast ? excl : beg + excl;    // cursor (LDS-rel or absolute)
    }
    __syncthreads();
    for (int i = beg + t; i < end; i += 1024) {
        int2 r = staging[i];
        int dlow = (unsigned)r.x >> 20;
        int sn = r.x & 0xFFFFF;
        float eav = __int_as_float(r.y);
        int pos = atomicAdd(&nh[dlow], 1);
        if (fast) {
            float lg = a_s1[sn] + a_d1[node0 + dlow] + eav * c1;
            lg = lg > 0.f ? lg : NEG_SLOPE * lg;
            ebuf[pos] = make_int2(sn, __float_as_int(__expf(lg)));
            abuf[pos] = eav;
        } else {
            sedge[pos] = make_int2(sn, __float_as_int(eav));
        }
    }
    __syncthreads();
    if (fast) {
        // write-out for agg2: (sn, eav)
        for (int j = t; j < cnt; j += 1024)
            sedge[beg + j] = make_int2(ebuf[j].x, __float_as_int(abuf[j]));
    }
    // ---------------- agg phase (layer-1 aggregation + fused gemm2) ----------------
    int g  = lane >> 3;          // node within wave (0..7)
    int fl = lane & 7;           // feature block
    int wv = t >> 6;
    float selfc = scal[0] * c1;
    const u16* hrow = h1b + fl * 8;
    #pragma unroll
    for (int rr = 0; rr < NPB / 128; rr++) {
        int dlow = rr * 128 + wv * 8 + g;
        int n = node0 + dlow;
        if (n >= N) continue;
        float den = 0.f;
        float acc[8] = {0.f, 0.f, 0.f, 0.f, 0.f, 0.f, 0.f, 0.f};
        if (fast) {
            int i = bg[dlow], i1 = nh[dlow];        // LDS-relative [beg,end)
            for (; i + 4 <= i1; i += 4) {
                int2 e0 = ebuf[i], e1 = ebuf[i + 1], e2 = ebuf[i + 2], e3 = ebuf[i + 3];
                int4 h0 = *(const int4*)(hrow + (size_t)e0.x * H);
                int4 h1v = *(const int4*)(hrow + (size_t)e1.x * H);
                int4 h2v = *(const int4*)(hrow + (size_t)e2.x * H);
                int4 h3v = *(const int4*)(hrow + (size_t)e3.x * H);
                accum8(acc, den, __int_as_float(e0.y), h0);
                accum8(acc, den, __int_as_float(e1.y), h1v);
                accum8(acc, den, __int_as_float(e2.y), h2v);
                accum8(acc, den, __int_as_float(e3.y), h3v);
            }
            for (; i < i1; i++) {
                int2 e0 = ebuf[i];
                int4 h0 = *(const int4*)(hrow + (size_t)e0.x * H);
                accum8(acc, den, __int_as_float(e0.y), h0);
            }
        } else {
            // fallback: edges in global sedge as (sn, eav); recompute ex
            int i = beg + bg[dlow], i1 = nh[dlow];  // absolute [beg,end)
            float adn = a_d1[n];
            for (; i < i1; i++) {
                int2 e0 = sedge[i];
                float lg = a_s1[e0.x] + adn + __int_as_float(e0.y) * c1;
                lg = lg > 0.f ? lg : NEG_SLOPE * lg;
                float ex = __expf(lg);
                int4 h0 = *(const int4*)(hrow + (size_t)e0.x * H);
                accum8(acc, den, ex, h0);
            }
        }
        // self loop (src = dst = n, edge_attr = mean)
        {
            float lg = a_s1[n] + a_d1[n] + selfc;
            lg = lg > 0.f ? lg : NEG_SLOPE * lg;
            float ex = __expf(lg);
            int4 hs = *(const int4*)(hrow + (size_t)n * H);
            accum8(acc, den, ex, hs);
        }
        // epilogue: divide, bias, relu, fused gemm2 over this lane's 8 features
        float inv = 1.f / (den + EPSF);
        float p0 = 0.f, p1 = 0.f;
        #pragma unroll
        for (int k = 0; k < 8; k++) {
            int f = fl * 8 + k;
            float hr = acc[k] * inv + bias1[f];
            hr = fmaxf(hr, 0.f);
            p0 += hr * W2[f * C + 0];
            p1 += hr * W2[f * C + 1];
        }
        #pragma unroll
        for (int msk = 1; msk < 8; msk <<= 1) {
            p0 += __shfl_xor(p0, msk, 64);
            p1 += __shfl_xor(p1, msk, 64);
        }
        if (fl == 0) {
            h2[(size_t)n * C + 0] = p0;
            h2[(size_t)n * C + 1] = p1;
            a_s2[n] = p0 * att_src2[0] + p1 * att_src2[1];
            a_d2[n] = p0 * att_dst2[0] + p1 * att_dst2[1];
        }
    }
}

// ---------- layer 2 aggregation: 8-lane group per dst node + log_softmax ----------
// sedge holds (sn, eav) — one 8B load per edge.
__global__ __launch_bounds__(256) void agg2_kernel(
        const int* __restrict__ row, const int2* __restrict__ sedge,
        const float* __restrict__ scal,
        const float* __restrict__ a_s2, const float* __restrict__ a_d2,
        const float* __restrict__ h2, const float* __restrict__ bias2,
        float* __restrict__ out, int N) {
    int wv = threadIdx.x >> 6;
    int lane = threadIdx.x & 63;
    int g  = lane >> 3;
    int fl = lane & 7;
    int n = blockIdx.x * 32 + wv * 8 + g;
    if (n >= N) return;
    float c2 = scal[2];
    float ad = a_d2[n];
    int beg = row[n], end = row[n + 1];
    float den = 0.f, m0 = 0.f, m1 = 0.f;
    for (int i = beg + fl; i < end; i += 8) {
        int2 e = sedge[i];
        int s = e.x;
        float lg = a_s2[s] + ad + __int_as_float(e.y) * c2;
        lg = lg > 0.f ? lg : NEG_SLOPE * lg;
        float ex = __expf(lg);
        den += ex;
        m0 += ex * h2[(size_t)s * C + 0];
        m1 += ex * h2[(size_t)s * C + 1];
    }
    if (fl == 0) {   // self loop
        float lg = a_s2[n] + ad + scal[0] * c2;
        lg = lg > 0.f ? lg : NEG_SLOPE * lg;
        float ex = __expf(lg);
        den += ex;
        m0 += ex * h2[(size_t)n * C + 0];
        m1 += ex * h2[(size_t)n * C + 1];
    }
    #pragma unroll
    for (int msk = 1; msk < 8; msk <<= 1) {
        den += __shfl_xor(den, msk, 64);
        m0  += __shfl_xor(m0, msk, 64);
        m1  += __shfl_xor(m1, msk, 64);
    }
    if (fl == 0) {
        float dn = den + EPSF;
        float o0 = m0 / dn + bias2[0];
        float o1 = m1 / dn + bias2[1];
        float mx = fmaxf(o0, o1);
        float lse = mx + logf(expf(o0 - mx) + expf(o1 - mx));
        out[(size_t)n * C + 0] = o0 - lse;
        out[(size_t)n * C + 1] = o1 - lse;
    }
}

extern "C" void kernel_launch(void* const* d_in, const int* in_sizes, int n_in,
                              void* d_out, int out_size, void* d_ws, size_t ws_size,
                              hipStream_t stream) {
    const float* x        = (const float*)d_in[0];
    const int*   ei       = (const int*)d_in[1];
    const float* ea       = (const float*)d_in[2];
    const float* W1       = (const float*)d_in[3];
    const float* att_src1 = (const float*)d_in[4];
    const float* att_dst1 = (const float*)d_in[5];
    const float* W_edge1  = (const float*)d_in[6];
    const float* att_edge1= (const float*)d_in[7];
    const float* bias1    = (const float*)d_in[8];
    const float* W2       = (const float*)d_in[9];
    const float* att_src2 = (const float*)d_in[10];
    const float* att_dst2 = (const float*)d_in[11];
    const float* W_edge2  = (const float*)d_in[12];
    const float* att_edge2= (const float*)d_in[13];
    const float* bias2    = (const float*)d_in[14];

    const int N  = in_sizes[0] / FIN;
    const int E  = in_sizes[1] / 2;
    const int* srcp = ei;
    const int* dstp = ei + E;
    const int NBUCK  = (N + NPB - 1) >> BSHIFT;             // 782 for N=100k
    const int NCHUNK = (E + CHUNK - 1) / CHUNK;             // 391 for E=1.6M

    char* wsb = (char*)d_ws;
    size_t off = 0;
    auto alloc = [&](size_t bytes) { void* p = wsb + off; off += (bytes + 255) & ~size_t(255); return p; };
    float* csum   = (float*)alloc((size_t)2048 * 4);        // per-chunk ea sums
    int*   bcount = (int*)alloc((size_t)NBUCK_MAX * 4);
    int*   bbase  = (int*)alloc((size_t)(NBUCK_MAX + 1) * 4);
    int*   cnt    = (int*)alloc((size_t)NCHUNK * NBUCK * 4);
    int*   poff   = (int*)alloc((size_t)NBUCK * NCHUNK * 4);
    int*   row    = (int*)alloc((size_t)(N + 1) * 4);
    int2*  sedge  = (int2*)alloc((size_t)(E + 8) * 8);
    int2*  staging= (int2*)alloc((size_t)E * 8);
    u16*   h1b    = (u16*)alloc((size_t)N * H * 2);
    u16*   Wt_hi  = (u16*)alloc((size_t)FIN * H * 2);
    u16*   Wt_lo  = (u16*)alloc((size_t)FIN * H * 2);
    float* a_s1   = (float*)alloc((size_t)N * 4);
    float* a_d1   = (float*)alloc((size_t)N * 4);
    float* h2     = (float*)alloc((size_t)N * C * 4);
    float* a_s2   = (float*)alloc((size_t)N * 4);
    float* a_d2   = (float*)alloc((size_t)N * 4);
    float* scal   = (float*)alloc(3 * 4);

    pre_kernel<<<NCHUNK, 1024, 0, stream>>>(ea, dstp, E, csum, cnt, W1, Wt_hi, Wt_lo, NBUCK);
    soff_kernel<<<NBUCK, 256, 0, stream>>>(cnt, NBUCK, NCHUNK, bcount, poff,
                                           csum, E, W_edge1, att_edge1, W_edge2, att_edge2,
                                           scal, row + N);
    stage_kernel<<<NCHUNK, 1024, 0, stream>>>(srcp, dstp, ea, E, cnt, poff, bcount,
                                              staging, bbase, NBUCK, NCHUNK);
    gemm1_mfma_kernel<<<(N + 127) / 128, 256, 0, stream>>>(x, Wt_hi, Wt_lo, att_src1, att_dst1,
                                                           h1b, a_s1, a_d1, N);
    bfin_agg1_kernel<<<NBUCK, 1024, 0, stream>>>(staging, bbase, scal, a_s1, a_d1, h1b,
                                                 bias1, W2, att_src2, att_dst2,
                                                 row, sedge, h2, a_s2, a_d2, N);
    agg2_kernel<<<(N + 31) / 32, 256, 0, stream>>>(row, sedge, scal, a_s2, a_d2, h2, bias2,
                                                   (float*)d_out, N);
}

// Round 11
// 200.721 us; speedup vs baseline: 1.0767x; 1.0767x over previous
//
#include <hip/hip_runtime.h>
#include <math.h>

#define NEG_SLOPE 0.2f
#define EPSF 1e-16f

constexpr int FIN = 128;
constexpr int H   = 64;
constexpr int C   = 2;
constexpr int BSHIFT = 8;               // nodes per bucket = 256 (best: round 9)
constexpr int NPB = 1 << BSHIFT;        // nodes per bucket
constexpr int NBUCK_MAX = 1024;         // supports N <= 256k at BSHIFT=8
constexpr int CHUNK = 4096;             // edges per stage block
constexpr int CAP   = 6144;             // max edges per bucket for LDS fast path

typedef short v8s __attribute__((ext_vector_type(8)));
typedef float v4f __attribute__((ext_vector_type(4)));
typedef unsigned short u16;

// round-to-nearest-even fp32 -> bf16 split (hi + lo captures ~17 mantissa bits)
__device__ inline void split_bf16(float v, u16& hi, u16& lo) {
    unsigned u = __float_as_uint(v);
    unsigned r = (u + 0x7FFFu + ((u >> 16) & 1u)) >> 16;
    hi = (u16)r;
    float hf = __uint_as_float(r << 16);
    float l = v - hf;
    unsigned ul = __float_as_uint(l);
    lo = (u16)((ul + 0x7FFFu + ((ul >> 16) & 1u)) >> 16);
}

__device__ inline u16 to_bf16(float v) {
    unsigned u = __float_as_uint(v);
    return (u16)((u + 0x7FFFu + ((u >> 16) & 1u)) >> 16);
}
__device__ inline float blo(int v) { return __uint_as_float((unsigned)v << 16); }
__device__ inline float bhi(int v) { return __uint_as_float((unsigned)v & 0xFFFF0000u); }

// exclusive prefix over a 1024-thread block via wave shfl scans.
// wtot must be 16 ints of LDS. Internal barrier; caller must barrier before
// reusing wtot.
__device__ inline int scan1024_excl(int v, int* wtot, int t) {
    int lane = t & 63, w = t >> 6;
    int incl = v;
    #pragma unroll
    for (int o = 1; o < 64; o <<= 1) {
        int u = __shfl_up(incl, o, 64);
        if (lane >= o) incl += u;
    }
    if (lane == 63) wtot[w] = incl;
    __syncthreads();
    int woff = 0;
    for (int i = 0; i < w; i++) woff += wtot[i];
    return woff + incl - v;
}

// ---------- pre: one chunk per block (1024 thr). ea chunk-sum + histogram + W1 prep ----------
// Wt is written in MFMA *fragment order*: element (k, f) -> flat u16 index
//   (k>>3)*512 + f*8 + (k&7)
__global__ __launch_bounds__(1024) void pre_kernel(const float* __restrict__ ea,
                                                   const int* __restrict__ dst, int E,
                                                   float* __restrict__ csum, int* __restrict__ cnt,
                                                   const float* __restrict__ W1,
                                                   u16* __restrict__ Wt_hi, u16* __restrict__ Wt_lo,
                                                   int NBUCK) {
    int c = blockIdx.x, t = threadIdx.x;
    int gid = c * 1024 + t;
    if (gid < FIN * H) {                      // W1 prep: first 8 blocks
        int k = gid >> 6, f = gid & 63;       // W1 is [k][f]
        u16 h, l;
        split_bf16(W1[gid], h, l);
        int idx = ((k >> 3) << 9) + (f << 3) + (k & 7);   // fragment order
        Wt_hi[idx] = h;
        Wt_lo[idx] = l;
    }
    __shared__ int lh[NBUCK_MAX];
    __shared__ float wsum[16];
    lh[t] = 0;
    __syncthreads();
    int base = c * CHUNK;
    int cntE = min(CHUNK, E - base);
    float acc = 0.f;
    for (int i = t; i < cntE; i += 1024) {
        int e = base + i;
        acc += ea[e];
        atomicAdd(&lh[dst[e] >> BSHIFT], 1);
    }
    for (int off = 32; off; off >>= 1) acc += __shfl_down(acc, off, 64);
    int lane = t & 63, wv = t >> 6;
    if (lane == 0) wsum[wv] = acc;
    __syncthreads();                          // covers lh atomics + wsum
    if (t == 0) {
        float s = 0.f;
        #pragma unroll
        for (int i = 0; i < 16; i++) s += wsum[i];
        csum[c] = s;                          // plain store, no global atomic
    }
    if (t < NBUCK) cnt[(size_t)c * NBUCK + t] = lh[t];
}

// ---------- soff: per-bucket scan over chunks -> poff[b][c], bcount[b]; block 0: scalars ----------
__global__ __launch_bounds__(256) void soff_kernel(const int* __restrict__ cnt,
                                                   int NBUCK, int NCHUNK,
                                                   int* __restrict__ bcount, int* __restrict__ poff,
                                                   const float* __restrict__ csum, int E,
                                                   const float* __restrict__ W_edge1,
                                                   const float* __restrict__ att_edge1,
                                                   const float* __restrict__ W_edge2,
                                                   const float* __restrict__ att_edge2,
                                                   float* __restrict__ scal,
                                                   int* __restrict__ rowN) {
    int b = blockIdx.x, t = threadIdx.x;
    int per = (NCHUNK + 255) / 256;           // chunks per thread (2 for NCHUNK=391)
    int v[8];                                 // supports NCHUNK <= 2048
    int s = 0;
    for (int j = 0; j < per; j++) {
        int c = t * per + j;
        v[j] = (c < NCHUNK) ? cnt[(size_t)c * NBUCK + b] : 0;
        s += v[j];
    }
    __shared__ int red[256];
    __shared__ float ws4[4];
    red[t] = s;
    __syncthreads();
    for (int off = 1; off < 256; off <<= 1) {
        int u = (t >= off) ? red[t - off] : 0;
        __syncthreads();
        red[t] += u;
        __syncthreads();
    }
    int run = red[t] - s;
    for (int j = 0; j < per; j++) {
        int c = t * per + j;
        if (c < NCHUNK) poff[(size_t)b * NCHUNK + c] = run;
        run += v[j];
    }
    if (t == 255) bcount[b] = red[255];
    if (b == 0) {                             // absorbed scalar work
        float acc = 0.f;
        for (int i = t; i < NCHUNK; i += 256) acc += csum[i];
        for (int off = 32; off; off >>= 1) acc += __shfl_down(acc, off, 64);
        if ((t & 63) == 0) ws4[t >> 6] = acc;
        __syncthreads();
        if (t == 0) {
            float tot = ws4[0] + ws4[1] + ws4[2] + ws4[3];
            float c1 = 0.f;
            for (int i = 0; i < H; i++) c1 += W_edge1[i] * att_edge1[i];
            float c2 = 0.f;
            for (int i = 0; i < C; i++) c2 += W_edge2[i] * att_edge2[i];
            scal[0] = tot / (float)E; scal[1] = c1; scal[2] = c2;
            *rowN = E;
        }
    }
}

// ---------- stage: bucket-major reorder (1024 thr); block 0 publishes bbase ----------
__global__ __launch_bounds__(1024) void stage_kernel(
        const int* __restrict__ src, const int* __restrict__ dst, const float* __restrict__ ea,
        int E, const int* __restrict__ cnt, const int* __restrict__ poff,
        const int* __restrict__ bcount,
        int2* __restrict__ staging, int* __restrict__ bbase_out, int NBUCK, int NCHUNK) {
    __shared__ int   bb[NBUCK_MAX];
    __shared__ int   cur[NBUCK_MAX];
    __shared__ int   gofs[NBUCK_MAX];
    __shared__ int2  sbuf[CHUNK];
    __shared__ short sbkt[CHUNK];
    __shared__ int   wt16[16];
    int t = threadIdx.x;
    int c = blockIdx.x;
    int base = c * CHUNK;
    int cntE = min(CHUNK, E - base);
    // in-block exclusive scan of bucket totals -> bb
    int bv = (t < NBUCK) ? bcount[t] : 0;
    int bx = scan1024_excl(bv, wt16, t);
    if (t < NBUCK) bb[t] = bx;
    if (c == 0) {                             // publish for bfin_agg1 (runs after stage)
        if (t < NBUCK) bbase_out[t] = bx;
        if (t == 0) bbase_out[NBUCK] = E;
    }
    __syncthreads();                          // wt16 reuse + bb visibility
    // local per-chunk histogram scan (1 bucket/thread)
    int h = (t < NBUCK) ? cnt[(size_t)c * NBUCK + t] : 0;
    int p = scan1024_excl(h, wt16, t);
    if (t < NBUCK) {
        if (h) gofs[t] = bb[t] + poff[(size_t)t * NCHUNK + c] - p;
        cur[t] = p;
    }
    __syncthreads();
    // reorder into LDS
    for (int i = t; i < cntE; i += 1024) {
        int e = base + i;
        int d = dst[e];
        int b = d >> BSHIFT;
        int slot = atomicAdd(&cur[b], 1);
        sbuf[slot] = make_int2(src[e] | ((d & (NPB - 1)) << 20), __float_as_int(ea[e]));
        sbkt[slot] = (short)b;
    }
    __syncthreads();
    // coalesced write-out
    for (int j = t; j < cntE; j += 1024)
        staging[gofs[sbkt[j]] + j] = sbuf[j];
}

// ---------- layer 1 GEMM: 2 m-tiles per wave (32 nodes), W staged in LDS ----------
__global__ __launch_bounds__(256) void gemm1_mfma_kernel(
        const float* __restrict__ x,
        const u16* __restrict__ Wt_hi, const u16* __restrict__ Wt_lo,
        const float* __restrict__ att_src, const float* __restrict__ att_dst,
        u16* __restrict__ h1b, float* __restrict__ a_s, float* __restrict__ a_d, int N) {
    __shared__ u16 WhL[FIN * H];   // 16 KB, fragment-ordered
    __shared__ u16 WlL[FIN * H];   // 16 KB
    int t = threadIdx.x;
    int w = t >> 6, lane = t & 63;
    int m = lane & 15, q = lane >> 4;
    int base = blockIdx.x * 128 + w * 32;    // wave owns 32 nodes (2 tiles of 16)
    int n0 = base + m;                        // tile-0 A row
    int n1 = base + 16 + m;                   // tile-1 A row
    bool in0 = n0 < N, in1 = n1 < N;
    const float* xr0 = x + (size_t)n0 * FIN;
    const float* xr1 = x + (size_t)n1 * FIN;

    // issue W-fill loads (L2-resident, 32 KB/block) and both x-row loads so
    // their latencies overlap; split while loads land.
    float4 fh[4], fl4[4];
    {
        const float4* gh = (const float4*)Wt_hi;
        const float4* gl = (const float4*)Wt_lo;
        #pragma unroll
        for (int i = 0; i < 4; i++) {
            fh[i]  = gh[t + i * 256];
            fl4[i] = gl[t + i * 256];
        }
    }
    float4 xa[8], xb[8];
    #pragma unroll
    for (int kt = 0; kt < 4; kt++) {
        if (in0) {
            const float4* p = (const float4*)(xr0 + kt * 32 + q * 8);
            xa[kt * 2] = p[0]; xa[kt * 2 + 1] = p[1];
        } else {
            xa[kt * 2] = make_float4(0.f, 0.f, 0.f, 0.f);
            xa[kt * 2 + 1] = make_float4(0.f, 0.f, 0.f, 0.f);
        }
        if (in1) {
            const float4* p = (const float4*)(xr1 + kt * 32 + q * 8);
            xb[kt * 2] = p[0]; xb[kt * 2 + 1] = p[1];
        } else {
            xb[kt * 2] = make_float4(0.f, 0.f, 0.f, 0.f);
            xb[kt * 2 + 1] = make_float4(0.f, 0.f, 0.f, 0.f);
        }
    }
    {
        float4* sh = (float4*)WhL;
        float4* sl = (float4*)WlL;
        #pragma unroll
        for (int i = 0; i < 4; i++) {
            sh[t + i * 256] = fh[i];
            sl[t + i * 256] = fl4[i];
        }
    }

    v8s ah0[4], al0[4], ah1[4], al1[4];
    #pragma unroll
    for (int kt = 0; kt < 4; kt++) {
        float va[8], vb[8];
        va[0] = xa[kt*2].x; va[1] = xa[kt*2].y; va[2] = xa[kt*2].z; va[3] = xa[kt*2].w;
        va[4] = xa[kt*2+1].x; va[5] = xa[kt*2+1].y; va[6] = xa[kt*2+1].z; va[7] = xa[kt*2+1].w;
        vb[0] = xb[kt*2].x; vb[1] = xb[kt*2].y; vb[2] = xb[kt*2].z; vb[3] = xb[kt*2].w;
        vb[4] = xb[kt*2+1].x; vb[5] = xb[kt*2+1].y; vb[6] = xb[kt*2+1].z; vb[7] = xb[kt*2+1].w;
        #pragma unroll
        for (int j = 0; j < 8; j++) {
            u16 hb, lb;
            split_bf16(va[j], hb, lb);
            ah0[kt][j] = (short)hb; al0[kt][j] = (short)lb;
            split_bf16(vb[j], hb, lb);
            ah1[kt][j] = (short)hb; al1[kt][j] = (short)lb;
        }
    }
    __syncthreads();

    float ps0[4] = {0,0,0,0}, pd0[4] = {0,0,0,0};
    float ps1[4] = {0,0,0,0}, pd1[4] = {0,0,0,0};
    #pragma unroll
    for (int ft = 0; ft < 4; ft++) {
        v4f acc0 = {0.f, 0.f, 0.f, 0.f};
        v4f acc1 = {0.f, 0.f, 0.f, 0.f};
        #pragma unroll
        for (int kt = 0; kt < 4; kt++) {
            // fragment (ft,kt,q,m): u16 index (kt*4+q)*512 + (ft*16+m)*8
            int fi = ((kt * 4 + q) << 9) + ((ft * 16 + m) << 3);
            v8s bh = *(const v8s*)(WhL + fi);
            v8s bl = *(const v8s*)(WlL + fi);
            acc0 = __builtin_amdgcn_mfma_f32_16x16x32_bf16(ah0[kt], bh, acc0, 0, 0, 0);
            acc0 = __builtin_amdgcn_mfma_f32_16x16x32_bf16(al0[kt], bh, acc0, 0, 0, 0);
            acc0 = __builtin_amdgcn_mfma_f32_16x16x32_bf16(ah0[kt], bl, acc0, 0, 0, 0);
            acc1 = __builtin_amdgcn_mfma_f32_16x16x32_bf16(ah1[kt], bh, acc1, 0, 0, 0);
            acc1 = __builtin_amdgcn_mfma_f32_16x16x32_bf16(al1[kt], bh, acc1, 0, 0, 0);
            acc1 = __builtin_amdgcn_mfma_f32_16x16x32_bf16(ah1[kt], bl, acc1, 0, 0, 0);
        }
        int f = ft * 16 + m;               // C col
        float asf = att_src[f], adf = att_dst[f];
        #pragma unroll
        for (int r = 0; r < 4; r++) {      // C row = q*4 + r within each tile
            int nd0 = base + q * 4 + r;
            int nd1 = base + 16 + q * 4 + r;
            if (nd0 < N) h1b[(size_t)nd0 * H + f] = to_bf16(acc0[r]);
            if (nd1 < N) h1b[(size_t)nd1 * H + f] = to_bf16(acc1[r]);
            ps0[r] += acc0[r] * asf; pd0[r] += acc0[r] * adf;
            ps1[r] += acc1[r] * asf; pd1[r] += acc1[r] * adf;
        }
    }
    #pragma unroll
    for (int msk = 1; msk < 16; msk <<= 1) {
        #pragma unroll
        for (int r = 0; r < 4; r++) {
            ps0[r] += __shfl_xor(ps0[r], msk, 64);
            pd0[r] += __shfl_xor(pd0[r], msk, 64);
            ps1[r] += __shfl_xor(ps1[r], msk, 64);
            pd1[r] += __shfl_xor(pd1[r], msk, 64);
        }
    }
    if (m == 0) {
        #pragma unroll
        for (int r = 0; r < 4; r++) {
            int nd0 = base + q * 4 + r;
            int nd1 = base + 16 + q * 4 + r;
            if (nd0 < N) { a_s[nd0] = ps0[r]; a_d[nd0] = pd0[r]; }
            if (nd1 < N) { a_s[nd1] = ps1[r]; a_d[nd1] = pd1[r]; }
        }
    }
}

__device__ inline void accum8(float acc[8], float& den, float xw, int4 hv) {
    den += xw;
    acc[0] += xw * blo(hv.x); acc[1] += xw * bhi(hv.x);
    acc[2] += xw * blo(hv.y); acc[3] += xw * bhi(hv.y);
    acc[4] += xw * blo(hv.z); acc[5] += xw * bhi(hv.z);
    acc[6] += xw * blo(hv.w); acc[7] += xw * bhi(hv.w);
}

// ---------- bfin+agg1 fused (1024 thr): CSR rows + LDS sort + ex1 + layer1 agg + gemm2 ----------
// One block per 256-node bucket. Sort phase keeps (sn,ex) in LDS, eav in abuf;
// sedge is written as (sn, eav) for agg2. Agg phase consumes the LDS edge list
// directly: 8-lane group per dst node, two 128-group rounds.
// Epilogue packs (a_s2, h2_0, h2_1) into one float4 ninfo row so agg2's
// per-edge random access is a single 16-B gather.
__global__ __launch_bounds__(1024) void bfin_agg1_kernel(
        const int2* __restrict__ staging, const int* __restrict__ bbase,
        const float* __restrict__ scal,
        const float* __restrict__ a_s1, const float* __restrict__ a_d1,
        const u16* __restrict__ h1b,
        const float* __restrict__ bias1, const float* __restrict__ W2,
        const float* __restrict__ att_src2, const float* __restrict__ att_dst2,
        int* __restrict__ row, int2* __restrict__ sedge,
        float4* __restrict__ ninfo, float* __restrict__ a_d2, int N) {
    __shared__ int   nh[256];
    __shared__ int   bg[256];
    __shared__ int   wt16[16];
    __shared__ int2  ebuf[CAP];    // 48 KB: (sn, ex)
    __shared__ float abuf[CAP];    // 24 KB: eav
    int b = blockIdx.x, t = threadIdx.x;
    int beg = bbase[b], end = bbase[b + 1];
    int cnt = end - beg;
    int node0 = b << BSHIFT;
    float c1 = scal[1];
    if (t < 256) nh[t] = 0;
    __syncthreads();
    for (int i = beg + t; i < end; i += 1024)
        atomicAdd(&nh[(unsigned)staging[i].x >> 20], 1);
    __syncthreads();
    // exclusive scan over the 256 bins (first 4 waves carry the data)
    int v = (t < 256) ? nh[t] : 0;
    int lane = t & 63, w = t >> 6;
    int incl = v;
    #pragma unroll
    for (int o = 1; o < 64; o <<= 1) {
        int u = __shfl_up(incl, o, 64);
        if (lane >= o) incl += u;
    }
    if (w < 4 && lane == 63) wt16[w] = incl;
    __syncthreads();
    int woff = 0;
    int wl = w < 4 ? w : 4;
    for (int i = 0; i < wl; i++) woff += wt16[i];
    int excl = woff + incl - v;             // valid for t < 256
    if (t < NPB && node0 + t < N) row[node0 + t] = beg + excl;
    bool fast = (cnt <= CAP);
    if (t < 256) {
        bg[t] = excl;                        // start (relative for fast, offset for fallback)
        nh[t] = fast ? excl : beg + excl;    // cursor (LDS-rel or absolute)
    }
    __syncthreads();
    for (int i = beg + t; i < end; i += 1024) {
        int2 r = staging[i];
        int dlow = (unsigned)r.x >> 20;
        int sn = r.x & 0xFFFFF;
        float eav = __int_as_float(r.y);
        int pos = atomicAdd(&nh[dlow], 1);
        if (fast) {
            float lg = a_s1[sn] + a_d1[node0 + dlow] + eav * c1;
            lg = lg > 0.f ? lg : NEG_SLOPE * lg;
            ebuf[pos] = make_int2(sn, __float_as_int(__expf(lg)));
            abuf[pos] = eav;
        } else {
            sedge[pos] = make_int2(sn, __float_as_int(eav));
        }
    }
    __syncthreads();
    if (fast) {
        // write-out for agg2: (sn, eav)
        for (int j = t; j < cnt; j += 1024)
            sedge[beg + j] = make_int2(ebuf[j].x, __float_as_int(abuf[j]));
    }
    // ---------------- agg phase (layer-1 aggregation + fused gemm2) ----------------
    int g  = lane >> 3;          // node within wave (0..7)
    int fl = lane & 7;           // feature block
    int wv = t >> 6;
    float selfc = scal[0] * c1;
    const u16* hrow = h1b + fl * 8;
    #pragma unroll
    for (int rr = 0; rr < NPB / 128; rr++) {
        int dlow = rr * 128 + wv * 8 + g;
        int n = node0 + dlow;
        if (n >= N) continue;
        float den = 0.f;
        float acc[8] = {0.f, 0.f, 0.f, 0.f, 0.f, 0.f, 0.f, 0.f};
        if (fast) {
            int i = bg[dlow], i1 = nh[dlow];        // LDS-relative [beg,end)
            for (; i + 4 <= i1; i += 4) {
                int2 e0 = ebuf[i], e1 = ebuf[i + 1], e2 = ebuf[i + 2], e3 = ebuf[i + 3];
                int4 h0 = *(const int4*)(hrow + (size_t)e0.x * H);
                int4 h1v = *(const int4*)(hrow + (size_t)e1.x * H);
                int4 h2v = *(const int4*)(hrow + (size_t)e2.x * H);
                int4 h3v = *(const int4*)(hrow + (size_t)e3.x * H);
                accum8(acc, den, __int_as_float(e0.y), h0);
                accum8(acc, den, __int_as_float(e1.y), h1v);
                accum8(acc, den, __int_as_float(e2.y), h2v);
                accum8(acc, den, __int_as_float(e3.y), h3v);
            }
            for (; i < i1; i++) {
                int2 e0 = ebuf[i];
                int4 h0 = *(const int4*)(hrow + (size_t)e0.x * H);
                accum8(acc, den, __int_as_float(e0.y), h0);
            }
        } else {
            // fallback: edges in global sedge as (sn, eav); recompute ex
            int i = beg + bg[dlow], i1 = nh[dlow];  // absolute [beg,end)
            float adn = a_d1[n];
            for (; i < i1; i++) {
                int2 e0 = sedge[i];
                float lg = a_s1[e0.x] + adn + __int_as_float(e0.y) * c1;
                lg = lg > 0.f ? lg : NEG_SLOPE * lg;
                float ex = __expf(lg);
                int4 h0 = *(const int4*)(hrow + (size_t)e0.x * H);
                accum8(acc, den, ex, h0);
            }
        }
        // self loop (src = dst = n, edge_attr = mean)
        {
            float lg = a_s1[n] + a_d1[n] + selfc;
            lg = lg > 0.f ? lg : NEG_SLOPE * lg;
            float ex = __expf(lg);
            int4 hs = *(const int4*)(hrow + (size_t)n * H);
            accum8(acc, den, ex, hs);
        }
        // epilogue: divide, bias, relu, fused gemm2 over this lane's 8 features
        float inv = 1.f / (den + EPSF);
        float p0 = 0.f, p1 = 0.f;
        #pragma unroll
        for (int k = 0; k < 8; k++) {
            int f = fl * 8 + k;
            float hr = acc[k] * inv + bias1[f];
            hr = fmaxf(hr, 0.f);
            p0 += hr * W2[f * C + 0];
            p1 += hr * W2[f * C + 1];
        }
        #pragma unroll
        for (int msk = 1; msk < 8; msk <<= 1) {
            p0 += __shfl_xor(p0, msk, 64);
            p1 += __shfl_xor(p1, msk, 64);
        }
        if (fl == 0) {
            ninfo[n] = make_float4(p0 * att_src2[0] + p1 * att_src2[1], p0, p1, 0.f);
            a_d2[n] = p0 * att_dst2[0] + p1 * att_dst2[1];
        }
    }
}

// ---------- layer 2 aggregation: 8-lane group per dst node + log_softmax ----------
// sedge holds (sn, eav); ninfo[s] = (a_s2, h2_0, h2_1, _) — one 16-B gather/edge.
__global__ __launch_bounds__(256) void agg2_kernel(
        const int* __restrict__ row, const int2* __restrict__ sedge,
        const float* __restrict__ scal,
        const float4* __restrict__ ninfo, const float* __restrict__ a_d2,
        const float* __restrict__ bias2,
        float* __restrict__ out, int N) {
    int wv = threadIdx.x >> 6;
    int lane = threadIdx.x & 63;
    int g  = lane >> 3;
    int fl = lane & 7;
    int n = blockIdx.x * 32 + wv * 8 + g;
    if (n >= N) return;
    float c2 = scal[2];
    float ad = a_d2[n];
    int beg = row[n], end = row[n + 1];
    float den = 0.f, m0 = 0.f, m1 = 0.f;
    for (int i = beg + fl; i < end; i += 8) {
        int2 e = sedge[i];
        float4 nf = ninfo[e.x];
        float lg = nf.x + ad + __int_as_float(e.y) * c2;
        lg = lg > 0.f ? lg : NEG_SLOPE * lg;
        float ex = __expf(lg);
        den += ex;
        m0 += ex * nf.y;
        m1 += ex * nf.z;
    }
    if (fl == 0) {   // self loop
        float4 nf = ninfo[n];
        float lg = nf.x + ad + scal[0] * c2;
        lg = lg > 0.f ? lg : NEG_SLOPE * lg;
        float ex = __expf(lg);
        den += ex;
        m0 += ex * nf.y;
        m1 += ex * nf.z;
    }
    #pragma unroll
    for (int msk = 1; msk < 8; msk <<= 1) {
        den += __shfl_xor(den, msk, 64);
        m0  += __shfl_xor(m0, msk, 64);
        m1  += __shfl_xor(m1, msk, 64);
    }
    if (fl == 0) {
        float dn = den + EPSF;
        float o0 = m0 / dn + bias2[0];
        float o1 = m1 / dn + bias2[1];
        float mx = fmaxf(o0, o1);
        float lse = mx + logf(expf(o0 - mx) + expf(o1 - mx));
        out[(size_t)n * C + 0] = o0 - lse;
        out[(size_t)n * C + 1] = o1 - lse;
    }
}

extern "C" void kernel_launch(void* const* d_in, const int* in_sizes, int n_in,
                              void* d_out, int out_size, void* d_ws, size_t ws_size,
                              hipStream_t stream) {
    const float* x        = (const float*)d_in[0];
    const int*   ei       = (const int*)d_in[1];
    const float* ea       = (const float*)d_in[2];
    const float* W1       = (const float*)d_in[3];
    const float* att_src1 = (const float*)d_in[4];
    const float* att_dst1 = (const float*)d_in[5];
    const float* W_edge1  = (const float*)d_in[6];
    const float* att_edge1= (const float*)d_in[7];
    const float* bias1    = (const float*)d_in[8];
    const float* W2       = (const float*)d_in[9];
    const float* att_src2 = (const float*)d_in[10];
    const float* att_dst2 = (const float*)d_in[11];
    const float* W_edge2  = (const float*)d_in[12];
    const float* att_edge2= (const float*)d_in[13];
    const float* bias2    = (const float*)d_in[14];

    const int N  = in_sizes[0] / FIN;
    const int E  = in_sizes[1] / 2;
    const int* srcp = ei;
    const int* dstp = ei + E;
    const int NBUCK  = (N + NPB - 1) >> BSHIFT;             // 391 for N=100k
    const int NCHUNK = (E + CHUNK - 1) / CHUNK;             // 391 for E=1.6M

    char* wsb = (char*)d_ws;
    size_t off = 0;
    auto alloc = [&](size_t bytes) { void* p = wsb + off; off += (bytes + 255) & ~size_t(255); return p; };
    float* csum   = (float*)alloc((size_t)2048 * 4);        // per-chunk ea sums
    int*   bcount = (int*)alloc((size_t)NBUCK_MAX * 4);
    int*   bbase  = (int*)alloc((size_t)(NBUCK_MAX + 1) * 4);
    int*   cnt    = (int*)alloc((size_t)NCHUNK * NBUCK * 4);
    int*   poff   = (int*)alloc((size_t)NBUCK * NCHUNK * 4);
    int*   row    = (int*)alloc((size_t)(N + 1) * 4);
    int2*  sedge  = (int2*)alloc((size_t)(E + 8) * 8);
    int2*  staging= (int2*)alloc((size_t)E * 8);
    u16*   h1b    = (u16*)alloc((size_t)N * H * 2);
    u16*   Wt_hi  = (u16*)alloc((size_t)FIN * H * 2);
    u16*   Wt_lo  = (u16*)alloc((size_t)FIN * H * 2);
    float* a_s1   = (float*)alloc((size_t)N * 4);
    float* a_d1   = (float*)alloc((size_t)N * 4);
    float4* ninfo = (float4*)alloc((size_t)N * 16);
    float* a_d2   = (float*)alloc((size_t)N * 4);
    float* scal   = (float*)alloc(3 * 4);

    pre_kernel<<<NCHUNK, 1024, 0, stream>>>(ea, dstp, E, csum, cnt, W1, Wt_hi, Wt_lo, NBUCK);
    soff_kernel<<<NBUCK, 256, 0, stream>>>(cnt, NBUCK, NCHUNK, bcount, poff,
                                           csum, E, W_edge1, att_edge1, W_edge2, att_edge2,
                                           scal, row + N);
    stage_kernel<<<NCHUNK, 1024, 0, stream>>>(srcp, dstp, ea, E, cnt, poff, bcount,
                                              staging, bbase, NBUCK, NCHUNK);
    gemm1_mfma_kernel<<<(N + 127) / 128, 256, 0, stream>>>(x, Wt_hi, Wt_lo, att_src1, att_dst1,
                                                           h1b, a_s1, a_d1, N);
    bfin_agg1_kernel<<<NBUCK, 1024, 0, stream>>>(staging, bbase, scal, a_s1, a_d1, h1b,
                                                 bias1, W2, att_src2, att_dst2,
                                                 row, sedge, ninfo, a_d2, N);
    agg2_kernel<<<(N + 31) / 32, 256, 0, stream>>>(row, sedge, scal, ninfo, a_d2, bias2,
                                                   (float*)d_out, N);
}